// Round 5
// baseline (129.450 us; speedup 1.0000x reference)
//
#include <hip/hip_runtime.h>
#include <stdint.h>

#define Bn   8
#define CIN  64
#define Hh   128
#define Wh   128
#define COUT 64
#define Tt   9
#define HO   128
#define WO   128
#define HW   (HO * WO)

// LDS-staged region per block: 8x8 pixel tile, halo_y=5 / halo_x=4 =>
// 18x16 pixel records x 128 B = 36,864 B  ->  4 blocks/CU (vs R4's 50 KB
// which granularity-rounded to 2 blocks/CU, occupancy 21%).
#define RH     18
#define RWID   16
#define RREC   (RH * RWID)   // 288
#define HALO_Y 5
#define HALO_X 4

typedef _Float16 h16;
typedef __attribute__((ext_vector_type(2))) _Float16 h2;
typedef __attribute__((ext_vector_type(8))) _Float16 h8;
typedef __attribute__((ext_vector_type(4))) float   f4;

// Module-scope scratch (NOT d_ws: R1 overflowed ws_size and corrupted the
// harness's pristine inputs). 16 MiB fp16 NHWC x + 72 KiB fp16 weights.
__device__ h16 g_xT[(size_t)Bn * Hh * Wh * CIN];
__device__ h16 g_wh[Tt * COUT * CIN];

// ---------------------------------------------------------------------------
// prep: blocks [0,1024) transpose x NCHW fp32 -> g_xT NHWC fp16 (block per
// (b,y)); blocks [1024,1168) repack weight -> fp16 MFMA A-fragment order.
// ---------------------------------------------------------------------------
__global__ __launch_bounds__(256) void prep(const float* __restrict__ x,
                                            const float* __restrict__ w) {
    if (blockIdx.x >= Bn * Hh) {
        int tid = (blockIdx.x - Bn * Hh) * 256 + threadIdx.x;   // 36864
        int t   = tid >> 12;
        int rem = tid & 4095;
        int o   = rem >> 6;
        int c   = rem & 63;
        float v = w[(size_t)(o * 64 + c) * 9 + t];
        int ks = c >> 5, q = (c >> 3) & 3, j = c & 7;
        int mt = o >> 4, o15 = o & 15;
        g_wh[t * 4096 + ks * 2048 + mt * 512 + q * 128 + o15 * 8 + j] = (h16)v;
        return;
    }
    int b = blockIdx.x >> 7;
    int y = blockIdx.x & 127;
    __shared__ uint32_t tile[64][65];   // [c][x/2] packed fp16 pair

    const float* src = x + ((size_t)b * CIN) * (Hh * Wh) + (size_t)y * Wh;
    int t    = threadIdx.x;
    int xp   = t & 63;     // x-pair
    int csub = t >> 6;     // 0..3
    #pragma unroll
    for (int cc = 0; cc < 64; cc += 4) {
        int c = cc + csub;
        float2 v = *(const float2*)(src + (size_t)c * (Hh * Wh) + xp * 2);
        uint32_t h0 = (uint32_t)__builtin_bit_cast(uint16_t, (h16)v.x);
        uint32_t h1 = (uint32_t)__builtin_bit_cast(uint16_t, (h16)v.y);
        tile[c][xp] = h0 | (h1 << 16);
    }
    __syncthreads();

    uint32_t* dst = (uint32_t*)(g_xT + (((size_t)b * Hh + y) * Wh) * CIN);
    int d  = t & 31;
    int xo = t >> 5;
    #pragma unroll
    for (int it = 0; it < 16; ++it) {
        int xg = it * 8 + xo;
        uint32_t lo = tile[2 * d][xg >> 1];
        uint32_t hi = tile[2 * d + 1][xg >> 1];
        int sh = (xg & 1) * 16;
        uint32_t l0 = (lo >> sh) & 0xffffu;
        uint32_t h1 = (hi >> sh) & 0xffffu;
        dst[xg * 32 + d] = l0 | (h1 << 16);
    }
}

// ---------------------------------------------------------------------------
// dcn_main: 2048 blocks x 4 waves. Block tile = 8x8 pixels; wave w owns rows
// {2w,2w+1} x 8 cols (16 px) x all 64 COUT. x region staged in LDS with
// quad-XOR swizzle; bilinear corners via ds_read_b128. Halo (5,4): lanes with
// |dx|>~3 (~16% of wave-taps have >=1 such lane) take a few-lane global
// fallback. b = blk&7: XCD-affine L2 (2 MiB xT slice per XCD).
// ---------------------------------------------------------------------------
__global__ __launch_bounds__(256) void dcn_main(
        const float* __restrict__ offset, const float* __restrict__ mask,
        const float* __restrict__ bias, float* __restrict__ out) {
    __shared__ __align__(16) uint8_t sreg[RREC * 128];   // 36,864 B

    int blk  = blockIdx.x;
    int b    = blk & 7;
    int s    = blk >> 3;            // tile id within batch, 256 tiles
    int ty   = s >> 4, tx = s & 15;
    int i0   = ty * 8, j0 = tx * 8;
    int lane = threadIdx.x & 63;
    int wave = threadIdx.x >> 6;
    int n15  = lane & 15;
    int q    = lane >> 4;

    const h16* xb = g_xT + (size_t)b * (Hh * Wh * CIN);

    int i = i0 + (wave << 1) + (n15 >> 3);
    int j = j0 + (n15 & 7);
    int p = (i << 7) + j;

    // Hoisted before staging: independent loads overlap the stage latency.
    const float* offB = offset + (size_t)b * (2 * Tt * HW);
    const float* mskB = mask   + (size_t)b * (Tt * HW);
    float dyv[Tt], dxv[Tt], mmv[Tt];
    #pragma unroll
    for (int t = 0; t < Tt; ++t) {
        dyv[t] = offB[(2 * t) * HW + p];
        dxv[t] = offB[(2 * t + 1) * HW + p];
        mmv[t] = mskB[t * HW + p];
    }

    // ---- stage region: 288 records x 8 quads = 2304 uint4 = 9 x 256 ----
    {
        const int base_y = i0 - HALO_Y, base_x = j0 - HALO_X;
        #pragma unroll
        for (int it = 0; it < 9; ++it) {
            int idx  = it * 256 + threadIdx.x;
            int rec  = idx >> 3;
            int quad = idx & 7;
            int ry = rec >> 4, rx = rec & 15;
            int gy = min(max(base_y + ry, 0), Hh - 1);
            int gx = min(max(base_x + rx, 0), Wh - 1);
            uint4 v = *(const uint4*)(xb + ((gy << 7) + gx) * 64 + quad * 8);
            *(uint4*)(sreg + rec * 128 + ((quad ^ (rec & 7)) << 4)) = v;
        }
    }
    __syncthreads();

    f4 acc[4] = {{0.f,0.f,0.f,0.f},{0.f,0.f,0.f,0.f},
                 {0.f,0.f,0.f,0.f},{0.f,0.f,0.f,0.f}};

    #pragma unroll
    for (int t = 0; t < Tt; ++t) {
        const int ky = t / 3, kx = t % 3;
        float py = dyv[t] + (float)(i + ky - 1);
        float px = dxv[t] + (float)(j + kx - 1);
        float fy = floorf(py), fx = floorf(px);
        int   y0 = (int)fy,    x0 = (int)fx;
        float ly = py - fy,    lx = px - fx;
        float hy = 1.f - ly,   hx = 1.f - lx;

        bool vy0 = (y0 >= 0) && (y0 < Hh);
        bool vy1 = (y0 >= -1) && (y0 < Hh - 1);
        bool vx0 = (x0 >= 0) && (x0 < Wh);
        bool vx1 = (x0 >= -1) && (x0 < Wh - 1);
        float m = mmv[t];
        float w00 = (vy0 && vx0) ? hy * hx * m : 0.f;
        float w01 = (vy0 && vx1) ? hy * lx * m : 0.f;
        float w10 = (vy1 && vx0) ? ly * hx * m : 0.f;
        float w11 = (vy1 && vx1) ? ly * lx * m : 0.f;

        // region-local coords; corner+1 needs ry<=RH-2, rx<=RWID-2
        int ry = y0 - i0 + HALO_Y;
        int rx = x0 - j0 + HALO_X;
        bool intile = (ry >= 0) & (ry <= RH - 2) & (rx >= 0) & (rx <= RWID - 2);
        int ryc = min(max(ry, 0), RH - 2), rxc = min(max(rx, 0), RWID - 2);
        int pl00 = ryc * RWID + rxc;
        int pl01 = pl00 + 1, pl10 = pl00 + RWID, pl11 = pl00 + RWID + 1;

        union U4 { uint4 v; h2 h[4]; };
        U4 c00[2], c01[2], c10[2], c11[2];
        #pragma unroll
        for (int ks = 0; ks < 2; ++ks) {
            int qd = q + ks * 4;   // logical quad (16B) within 128B record
            c00[ks].v = *(const uint4*)(sreg + pl00 * 128 + ((qd ^ (pl00 & 7)) << 4));
            c01[ks].v = *(const uint4*)(sreg + pl01 * 128 + ((qd ^ (pl01 & 7)) << 4));
            c10[ks].v = *(const uint4*)(sreg + pl10 * 128 + ((qd ^ (pl10 & 7)) << 4));
            c11[ks].v = *(const uint4*)(sreg + pl11 * 128 + ((qd ^ (pl11 & 7)) << 4));
        }
        if (__any(!intile)) {   // few-lane global fallback (offset beyond halo)
            if (!intile) {
                int y0c = min(max(y0, 0), Hh - 1), y1c = min(max(y0 + 1, 0), Hh - 1);
                int x0c = min(max(x0, 0), Wh - 1), x1c = min(max(x0 + 1, 0), Wh - 1);
                const h16* r0 = xb + (size_t)(y0c * Wh) * CIN;
                const h16* r1 = xb + (size_t)(y1c * Wh) * CIN;
                #pragma unroll
                for (int ks = 0; ks < 2; ++ks) {
                    int c = q * 8 + ks * 32;
                    c00[ks].v = *(const uint4*)(r0 + x0c * CIN + c);
                    c01[ks].v = *(const uint4*)(r0 + x1c * CIN + c);
                    c10[ks].v = *(const uint4*)(r1 + x0c * CIN + c);
                    c11[ks].v = *(const uint4*)(r1 + x1c * CIN + c);
                }
            }
        }

        h2 W00 = {(h16)w00, (h16)w00};
        h2 W01 = {(h16)w01, (h16)w01};
        h2 W10 = {(h16)w10, (h16)w10};
        h2 W11 = {(h16)w11, (h16)w11};

        h8 bfrag[2];
        #pragma unroll
        for (int ks = 0; ks < 2; ++ks) {
            union { h2 r[4]; h8 v; } pk;
            #pragma unroll
            for (int e = 0; e < 4; ++e) {
                h2 r = c00[ks].h[e] * W00;
                r = c01[ks].h[e] * W01 + r;
                r = c10[ks].h[e] * W10 + r;
                r = c11[ks].h[e] * W11 + r;
                pk.r[e] = r;
            }
            bfrag[ks] = pk.v;
        }

        const h16* wt = g_wh + t * 4096;
        #pragma unroll
        for (int ks = 0; ks < 2; ++ks) {
            #pragma unroll
            for (int mt = 0; mt < 4; ++mt) {
                h8 a = *(const h8*)(wt + ks * 2048 + mt * 512 + lane * 8);
                acc[mt] = __builtin_amdgcn_mfma_f32_16x16x32_f16(
                    a, bfrag[ks], acc[mt], 0, 0, 0);
            }
        }
    }

    #pragma unroll
    for (int mt = 0; mt < 4; ++mt) {
        #pragma unroll
        for (int r = 0; r < 4; ++r) {
            int o = mt * 16 + q * 4 + r;
            out[(size_t)(b * COUT + o) * HW + p] = acc[mt][r] + bias[o];
        }
    }
}

extern "C" void kernel_launch(void* const* d_in, const int* in_sizes, int n_in,
                              void* d_out, int out_size, void* d_ws, size_t ws_size,
                              hipStream_t stream) {
    const float* x      = (const float*)d_in[0];
    const float* offset = (const float*)d_in[1];
    const float* mask   = (const float*)d_in[2];
    const float* weight = (const float*)d_in[3];
    const float* bias   = (const float*)d_in[4];
    (void)d_ws; (void)ws_size;

    prep<<<Bn * Hh + 144, 256, 0, stream>>>(x, weight);
    dcn_main<<<Bn * 256, 256, 0, stream>>>(offset, mask, bias, (float*)d_out);
}

// Round 6
// 122.265 us; speedup vs baseline: 1.0588x; 1.0588x over previous
//
#include <hip/hip_runtime.h>
#include <stdint.h>

#define Bn   8
#define CIN  64
#define Hh   128
#define Wh   128
#define COUT 64
#define Tt   9
#define HO   128
#define WO   128
#define HW   (HO * WO)

// Block tile = 8 rows x 16 cols of output pixels (128 px, 4 waves x 32 px,
// 32x32x16 MFMA). Staged region: halo_y=5, halo_x=4 -> 19 x 25 records of
// 128 B = 60,800 B LDS -> 2 blocks/CU. Width 25 == 1 (mod 8): same-column
// records land in different XOR-swizzle groups (R5's width 16 collided).
#define RH     19
#define RWC    25
#define RREC   (RH * RWC)    // 475
#define HALO_Y 5
#define HALO_X 4

typedef _Float16 h16;
typedef __attribute__((ext_vector_type(2)))  _Float16 h2;
typedef __attribute__((ext_vector_type(8)))  _Float16 h8;
typedef __attribute__((ext_vector_type(16))) float    f16v;

// Module-scope scratch (NOT d_ws: R1 overflowed ws_size and corrupted the
// harness's pristine inputs). 16 MiB fp16 NHWC x + 72 KiB fp16 weights.
__device__ h16 g_xT[(size_t)Bn * Hh * Wh * CIN];
__device__ h16 g_wh[Tt * 4 * 2 * 64 * 8];   // [t][ks][mt][lane][j]

// ---------------------------------------------------------------------------
// prep: blocks [0,1024) transpose x NCHW fp32 -> g_xT NHWC fp16 (block per
// (b,y)); blocks [1024,1168) repack weight -> fp16 32x32x16 A-frag order:
// a(t,ks,mt)[lane][j] = W[o = mt*32 + (lane&31)][c = ks*16 + (lane>>5)*8 + j]
// ---------------------------------------------------------------------------
__global__ __launch_bounds__(256) void prep(const float* __restrict__ x,
                                            const float* __restrict__ w) {
    if (blockIdx.x >= Bn * Hh) {
        int tid = (blockIdx.x - Bn * Hh) * 256 + threadIdx.x;   // 36864
        int t   = tid >> 12;
        int rem = tid & 4095;
        int ks  = rem >> 10;
        int mt  = (rem >> 9) & 1;
        int ln  = (rem >> 3) & 63;
        int j   = rem & 7;
        int o   = mt * 32 + (ln & 31);
        int c   = ks * 16 + ((ln >> 5) << 3) + j;
        g_wh[tid] = (h16)w[(size_t)(o * 64 + c) * 9 + t];
        return;
    }
    int b = blockIdx.x >> 7;
    int y = blockIdx.x & 127;
    __shared__ uint32_t tile[64][65];   // [c][x/2] packed fp16 pair

    const float* src = x + ((size_t)b * CIN) * (Hh * Wh) + (size_t)y * Wh;
    int t    = threadIdx.x;
    int xp   = t & 63;     // x-pair
    int csub = t >> 6;     // 0..3
    #pragma unroll
    for (int cc = 0; cc < 64; cc += 4) {
        int c = cc + csub;
        float2 v = *(const float2*)(src + (size_t)c * (Hh * Wh) + xp * 2);
        uint32_t h0 = (uint32_t)__builtin_bit_cast(uint16_t, (h16)v.x);
        uint32_t h1 = (uint32_t)__builtin_bit_cast(uint16_t, (h16)v.y);
        tile[c][xp] = h0 | (h1 << 16);
    }
    __syncthreads();

    uint32_t* dst = (uint32_t*)(g_xT + (((size_t)b * Hh + y) * Wh) * CIN);
    int d  = t & 31;
    int xo = t >> 5;
    #pragma unroll
    for (int it = 0; it < 16; ++it) {
        int xg = it * 8 + xo;
        uint32_t lo = tile[2 * d][xg >> 1];
        uint32_t hi = tile[2 * d + 1][xg >> 1];
        int sh = (xg & 1) * 16;
        uint32_t l0 = (lo >> sh) & 0xffffu;
        uint32_t h1 = (hi >> sh) & 0xffffu;
        dst[xg * 32 + d] = l0 | (h1 << 16);
    }
}

// ---------------------------------------------------------------------------
// dcn_main: 1024 blocks x 4 waves; wave owns 2 rows x 16 cols (32 px) x all
// 64 COUT via 2x v_mfma_f32_32x32x16_f16 per (tap,ks). Region in LDS with
// quad-XOR swizzle; weight a-frags: 8 global 16B loads serve 32 px (halved
// per-px TA vs 16x16 path — R5 analysis showed a-frag tag cycles were the
// largest TA component). b = blk&7: XCD-affine L2.
// ---------------------------------------------------------------------------
__global__ __launch_bounds__(256) void dcn_main(
        const float* __restrict__ offset, const float* __restrict__ mask,
        const float* __restrict__ bias, float* __restrict__ out) {
    __shared__ __align__(16) uint8_t sreg[RREC * 128];   // 60,800 B

    int blk  = blockIdx.x;
    int b    = blk & 7;
    int s    = blk >> 3;            // tile id within batch, 128 tiles
    int ty   = s >> 3, tx = s & 7;
    int i0   = ty * 8, j0 = tx * 16;
    int lane = threadIdx.x & 63;
    int wave = threadIdx.x >> 6;
    int n    = lane & 31;           // pixel within wave
    int g    = lane >> 5;           // channel group (8 ch)

    const h16* xb = g_xT + (size_t)b * (Hh * Wh * CIN);

    int i = i0 + 2 * wave + (n >> 4);
    int j = j0 + (n & 15);
    int p = (i << 7) + j;

    // Hoisted: independent of staging, overlaps its latency.
    const float* offB = offset + (size_t)b * (2 * Tt * HW);
    const float* mskB = mask   + (size_t)b * (Tt * HW);
    float dyv[Tt], dxv[Tt], mmv[Tt];
    #pragma unroll
    for (int t = 0; t < Tt; ++t) {
        dyv[t] = offB[(2 * t) * HW + p];
        dxv[t] = offB[(2 * t + 1) * HW + p];
        mmv[t] = mskB[t * HW + p];
    }

    // ---- stage region: 475 records x 8 quads = 3800 uint4 ----
    {
        const int base_y = i0 - HALO_Y, base_x = j0 - HALO_X;
        #pragma unroll
        for (int it = 0; it < 15; ++it) {
            int idx  = it * 256 + threadIdx.x;
            int rec  = idx >> 3;
            int quad = idx & 7;
            if (rec < RREC) {
                int ry = rec / RWC, rx = rec - ry * RWC;
                int gy = min(max(base_y + ry, 0), Hh - 1);
                int gx = min(max(base_x + rx, 0), Wh - 1);
                uint4 v = *(const uint4*)(xb + ((gy << 7) + gx) * 64 + quad * 8);
                *(uint4*)(sreg + rec * 128 + ((quad ^ (rec & 7)) << 4)) = v;
            }
        }
    }
    __syncthreads();

    f16v acc[2] = {};

    #pragma unroll
    for (int t = 0; t < Tt; ++t) {
        const int ky = t / 3, kx = t % 3;
        float py = dyv[t] + (float)(i + ky - 1);
        float px = dxv[t] + (float)(j + kx - 1);
        float fy = floorf(py), fx = floorf(px);
        int   y0 = (int)fy,    x0 = (int)fx;
        float ly = py - fy,    lx = px - fx;
        float hy = 1.f - ly,   hx = 1.f - lx;

        bool vy0 = (y0 >= 0) && (y0 < Hh);
        bool vy1 = (y0 >= -1) && (y0 < Hh - 1);
        bool vx0 = (x0 >= 0) && (x0 < Wh);
        bool vx1 = (x0 >= -1) && (x0 < Wh - 1);
        float m = mmv[t];
        float w00 = (vy0 && vx0) ? hy * hx * m : 0.f;
        float w01 = (vy0 && vx1) ? hy * lx * m : 0.f;
        float w10 = (vy1 && vx0) ? ly * hx * m : 0.f;
        float w11 = (vy1 && vx1) ? ly * lx * m : 0.f;

        // region-local coords; corner+1 needs ry<=RH-2, rx<=RWC-2
        int ry = y0 - i0 + HALO_Y;
        int rx = x0 - j0 + HALO_X;
        bool intile = (ry >= 0) & (ry <= RH - 2) & (rx >= 0) & (rx <= RWC - 2);
        int ryc = min(max(ry, 0), RH - 2), rxc = min(max(rx, 0), RWC - 2);
        int pl00 = ryc * RWC + rxc;
        int pl01 = pl00 + 1, pl10 = pl00 + RWC, pl11 = pl00 + RWC + 1;

        union U4 { uint4 v; h2 h[4]; };
        U4 c00[4], c01[4], c10[4], c11[4];
        #pragma unroll
        for (int ks = 0; ks < 4; ++ks) {
            int qd = ks * 2 + g;   // 16B quad holding ch ks*16+g*8 .. +8
            c00[ks].v = *(const uint4*)(sreg + pl00 * 128 + ((qd ^ (pl00 & 7)) << 4));
            c01[ks].v = *(const uint4*)(sreg + pl01 * 128 + ((qd ^ (pl01 & 7)) << 4));
            c10[ks].v = *(const uint4*)(sreg + pl10 * 128 + ((qd ^ (pl10 & 7)) << 4));
            c11[ks].v = *(const uint4*)(sreg + pl11 * 128 + ((qd ^ (pl11 & 7)) << 4));
        }
        if (__any(!intile)) {   // few-lane global fallback (offset beyond halo)
            if (!intile) {
                int y0c = min(max(y0, 0), Hh - 1), y1c = min(max(y0 + 1, 0), Hh - 1);
                int x0c = min(max(x0, 0), Wh - 1), x1c = min(max(x0 + 1, 0), Wh - 1);
                const h16* r0 = xb + (size_t)(y0c * Wh) * CIN;
                const h16* r1 = xb + (size_t)(y1c * Wh) * CIN;
                #pragma unroll
                for (int ks = 0; ks < 4; ++ks) {
                    int c = ks * 16 + g * 8;
                    c00[ks].v = *(const uint4*)(r0 + x0c * CIN + c);
                    c01[ks].v = *(const uint4*)(r0 + x1c * CIN + c);
                    c10[ks].v = *(const uint4*)(r1 + x0c * CIN + c);
                    c11[ks].v = *(const uint4*)(r1 + x1c * CIN + c);
                }
            }
        }

        h2 W00 = {(h16)w00, (h16)w00};
        h2 W01 = {(h16)w01, (h16)w01};
        h2 W10 = {(h16)w10, (h16)w10};
        h2 W11 = {(h16)w11, (h16)w11};

        const h16* wt = g_wh + t * 4096;
        #pragma unroll
        for (int ks = 0; ks < 4; ++ks) {
            union { h2 r[4]; h8 v; } pk;
            #pragma unroll
            for (int e = 0; e < 4; ++e) {
                h2 r = c00[ks].h[e] * W00;
                r = c01[ks].h[e] * W01 + r;
                r = c10[ks].h[e] * W10 + r;
                r = c11[ks].h[e] * W11 + r;
                pk.r[e] = r;
            }
            #pragma unroll
            for (int mt = 0; mt < 2; ++mt) {
                h8 a = *(const h8*)(wt + (ks * 2 + mt) * 512 + lane * 8);
                acc[mt] = __builtin_amdgcn_mfma_f32_32x32x16_f16(
                    a, pk.v, acc[mt], 0, 0, 0);
            }
        }
    }

    // C/D layout (32x32): col = lane&31 (= px), row = (r&3) + 8*(r>>2) + 4*g.
    #pragma unroll
    for (int mt = 0; mt < 2; ++mt) {
        #pragma unroll
        for (int r = 0; r < 16; ++r) {
            int o = mt * 32 + (r & 3) + 8 * (r >> 2) + 4 * g;
            out[(size_t)(b * COUT + o) * HW + p] = acc[mt][r] + bias[o];
        }
    }
}

extern "C" void kernel_launch(void* const* d_in, const int* in_sizes, int n_in,
                              void* d_out, int out_size, void* d_ws, size_t ws_size,
                              hipStream_t stream) {
    const float* x      = (const float*)d_in[0];
    const float* offset = (const float*)d_in[1];
    const float* mask   = (const float*)d_in[2];
    const float* weight = (const float*)d_in[3];
    const float* bias   = (const float*)d_in[4];
    (void)d_ws; (void)ws_size;

    prep<<<Bn * Hh + 144, 256, 0, stream>>>(x, weight);
    dcn_main<<<Bn * 128, 256, 0, stream>>>(offset, mask, bias, (float*)d_out);
}

// Round 7
// 121.534 us; speedup vs baseline: 1.0651x; 1.0060x over previous
//
#include <hip/hip_runtime.h>
#include <stdint.h>

#define Bn   8
#define CIN  64
#define Hh   128
#define Wh   128
#define COUT 64
#define Tt   9
#define HO   128
#define WO   128
#define HW   (HO * WO)

// Block tile = 8 rows x 16 cols of output pixels (128 px, 4 waves x 32 px,
// 32x32x16 MFMA). Staged region: halo (4,4) -> 17 x 25 records.
// Record stride = 144 B (128 B data + 16 B pad): record starts sweep all 32
// banks ((rec*36)&31), replacing R6's XOR swizzle -- kills ~4 VALU of address
// math per ds_read; all 16 corner reads per tap become immediate-offset
// ds_read_b128 off one per-tap base. 61,200 B LDS, 2 blocks/CU.
#define RH     17
#define RWC    25
#define RREC   (RH * RWC)    // 425
#define RSTR   144           // record stride bytes
#define HALO_Y 4
#define HALO_X 4

typedef _Float16 h16;
typedef __attribute__((ext_vector_type(2)))  _Float16 h2;
typedef __attribute__((ext_vector_type(8)))  _Float16 h8;
typedef __attribute__((ext_vector_type(16))) float    f16v;

// Module-scope scratch (NOT d_ws: R1 overflowed ws_size and corrupted the
// harness's pristine inputs). 16 MiB fp16 NHWC x + 72 KiB fp16 weights.
__device__ h16 g_xT[(size_t)Bn * Hh * Wh * CIN];
__device__ h16 g_wh[Tt * 4 * 2 * 64 * 8];   // [t][ks][mt][lane][j]

// ---------------------------------------------------------------------------
// prep: blocks [0,1024) transpose x NCHW fp32 -> g_xT NHWC fp16 (block per
// (b,y)); blocks [1024,1168) repack weight -> fp16 32x32x16 A-frag order:
// a(t,ks,mt)[lane][j] = W[o = mt*32 + (lane&31)][c = ks*16 + (lane>>5)*8 + j]
// ---------------------------------------------------------------------------
__global__ __launch_bounds__(256) void prep(const float* __restrict__ x,
                                            const float* __restrict__ w) {
    if (blockIdx.x >= Bn * Hh) {
        int tid = (blockIdx.x - Bn * Hh) * 256 + threadIdx.x;   // 36864
        int t   = tid >> 12;
        int rem = tid & 4095;
        int ks  = rem >> 10;
        int mt  = (rem >> 9) & 1;
        int ln  = (rem >> 3) & 63;
        int j   = rem & 7;
        int o   = mt * 32 + (ln & 31);
        int c   = ks * 16 + ((ln >> 5) << 3) + j;
        g_wh[tid] = (h16)w[(size_t)(o * 64 + c) * 9 + t];
        return;
    }
    int b = blockIdx.x >> 7;
    int y = blockIdx.x & 127;
    __shared__ uint32_t tile[64][65];   // [c][x/2] packed fp16 pair

    const float* src = x + ((size_t)b * CIN) * (Hh * Wh) + (size_t)y * Wh;
    int t    = threadIdx.x;
    int xp   = t & 63;     // x-pair
    int csub = t >> 6;     // 0..3
    #pragma unroll
    for (int cc = 0; cc < 64; cc += 4) {
        int c = cc + csub;
        float2 v = *(const float2*)(src + (size_t)c * (Hh * Wh) + xp * 2);
        uint32_t h0 = (uint32_t)__builtin_bit_cast(uint16_t, (h16)v.x);
        uint32_t h1 = (uint32_t)__builtin_bit_cast(uint16_t, (h16)v.y);
        tile[c][xp] = h0 | (h1 << 16);
    }
    __syncthreads();

    uint32_t* dst = (uint32_t*)(g_xT + (((size_t)b * Hh + y) * Wh) * CIN);
    int d  = t & 31;
    int xo = t >> 5;
    #pragma unroll
    for (int it = 0; it < 16; ++it) {
        int xg = it * 8 + xo;
        uint32_t lo = tile[2 * d][xg >> 1];
        uint32_t hi = tile[2 * d + 1][xg >> 1];
        int sh = (xg & 1) * 16;
        uint32_t l0 = (lo >> sh) & 0xffffu;
        uint32_t h1 = (hi >> sh) & 0xffffu;
        dst[xg * 32 + d] = l0 | (h1 << 16);
    }
}

// ---------------------------------------------------------------------------
// dcn_main: 1024 blocks x 4 waves; wave owns 2 rows x 16 cols (32 px) x all
// 64 COUT via 2x v_mfma_f32_32x32x16_f16 per (tap,ks). Region in LDS at
// 144-B record stride (bank sweep, immediate-offset reads). b = blk&7:
// XCD-affine L2.
// ---------------------------------------------------------------------------
__global__ __launch_bounds__(256) void dcn_main(
        const float* __restrict__ offset, const float* __restrict__ mask,
        const float* __restrict__ bias, float* __restrict__ out) {
    __shared__ __align__(16) uint8_t sreg[RREC * RSTR];   // 61,200 B

    int blk  = blockIdx.x;
    int b    = blk & 7;
    int s    = blk >> 3;            // tile id within batch, 128 tiles
    int ty   = s >> 3, tx = s & 7;
    int i0   = ty * 8, j0 = tx * 16;
    int lane = threadIdx.x & 63;
    int wave = threadIdx.x >> 6;
    int n    = lane & 31;           // pixel within wave
    int g    = lane >> 5;           // channel group (8 ch)

    const h16* xb = g_xT + (size_t)b * (Hh * Wh * CIN);

    int i = i0 + 2 * wave + (n >> 4);
    int j = j0 + (n & 15);
    int p = (i << 7) + j;

    // Hoisted: independent of staging, overlaps its latency.
    const float* offB = offset + (size_t)b * (2 * Tt * HW);
    const float* mskB = mask   + (size_t)b * (Tt * HW);
    float dyv[Tt], dxv[Tt], mmv[Tt];
    #pragma unroll
    for (int t = 0; t < Tt; ++t) {
        dyv[t] = offB[(2 * t) * HW + p];
        dxv[t] = offB[(2 * t + 1) * HW + p];
        mmv[t] = mskB[t * HW + p];
    }

    // ---- stage region: 425 records x 8 quads = 3400 uint4 ----
    {
        const int base_y = i0 - HALO_Y, base_x = j0 - HALO_X;
        #pragma unroll
        for (int it = 0; it < 14; ++it) {
            int idx  = it * 256 + threadIdx.x;
            int rec  = idx >> 3;
            int quad = idx & 7;
            if (rec < RREC) {
                int ry = rec / RWC, rx = rec - ry * RWC;
                int gy = min(max(base_y + ry, 0), Hh - 1);
                int gx = min(max(base_x + rx, 0), Wh - 1);
                uint4 v = *(const uint4*)(xb + ((gy << 7) + gx) * 64 + quad * 8);
                *(uint4*)(sreg + rec * RSTR + quad * 16) = v;
            }
        }
    }
    __syncthreads();

    f16v acc[2] = {};

    #pragma unroll
    for (int t = 0; t < Tt; ++t) {
        const int ky = t / 3, kx = t % 3;
        float py = dyv[t] + (float)(i + ky - 1);
        float px = dxv[t] + (float)(j + kx - 1);
        float fy = floorf(py), fx = floorf(px);
        int   y0 = (int)fy,    x0 = (int)fx;
        float ly = py - fy,    lx = px - fx;
        float hy = 1.f - ly,   hx = 1.f - lx;

        bool vy0 = (y0 >= 0) && (y0 < Hh);
        bool vy1 = (y0 >= -1) && (y0 < Hh - 1);
        bool vx0 = (x0 >= 0) && (x0 < Wh);
        bool vx1 = (x0 >= -1) && (x0 < Wh - 1);
        float m = mmv[t];
        float w00 = (vy0 && vx0) ? hy * hx * m : 0.f;
        float w01 = (vy0 && vx1) ? hy * lx * m : 0.f;
        float w10 = (vy1 && vx0) ? ly * hx * m : 0.f;
        float w11 = (vy1 && vx1) ? ly * lx * m : 0.f;

        // region-local record coords; corner+1 needs ry<=RH-2, rx<=RWC-2
        int ry = y0 - i0 + HALO_Y;
        int rx = x0 - j0 + HALO_X;
        bool intile = (ry >= 0) & (ry <= RH - 2) & (rx >= 0) & (rx <= RWC - 2);
        int ryc = min(max(ry, 0), RH - 2), rxc = min(max(rx, 0), RWC - 2);
        int pl00 = ryc * RWC + rxc;
        // One per-tap base; 16 reads at uniform immediate offsets.
        const uint8_t* cbase = sreg + pl00 * RSTR + g * 16;

        union U4 { uint4 v; h2 h[4]; };
        U4 c00[4], c01[4], c10[4], c11[4];
        #pragma unroll
        for (int ks = 0; ks < 4; ++ks) {
            c00[ks].v = *(const uint4*)(cbase + ks * 32);
            c01[ks].v = *(const uint4*)(cbase + RSTR + ks * 32);
            c10[ks].v = *(const uint4*)(cbase + RWC * RSTR + ks * 32);
            c11[ks].v = *(const uint4*)(cbase + (RWC + 1) * RSTR + ks * 32);
        }
        if (__any(!intile)) {   // few-lane global fallback (offset beyond halo)
            if (!intile) {
                int y0c = min(max(y0, 0), Hh - 1), y1c = min(max(y0 + 1, 0), Hh - 1);
                int x0c = min(max(x0, 0), Wh - 1), x1c = min(max(x0 + 1, 0), Wh - 1);
                const h16* r0 = xb + (size_t)(y0c * Wh) * CIN;
                const h16* r1 = xb + (size_t)(y1c * Wh) * CIN;
                #pragma unroll
                for (int ks = 0; ks < 4; ++ks) {
                    int c = ks * 16 + g * 8;
                    c00[ks].v = *(const uint4*)(r0 + x0c * CIN + c);
                    c01[ks].v = *(const uint4*)(r0 + x1c * CIN + c);
                    c10[ks].v = *(const uint4*)(r1 + x0c * CIN + c);
                    c11[ks].v = *(const uint4*)(r1 + x1c * CIN + c);
                }
            }
        }

        h2 W00 = {(h16)w00, (h16)w00};
        h2 W01 = {(h16)w01, (h16)w01};
        h2 W10 = {(h16)w10, (h16)w10};
        h2 W11 = {(h16)w11, (h16)w11};

        const h16* wt = g_wh + t * 4096;
        #pragma unroll
        for (int ks = 0; ks < 4; ++ks) {
            union { h2 r[4]; h8 v; } pk;
            #pragma unroll
            for (int e = 0; e < 4; ++e) {
                h2 r = c00[ks].h[e] * W00;
                r = c01[ks].h[e] * W01 + r;
                r = c10[ks].h[e] * W10 + r;
                r = c11[ks].h[e] * W11 + r;
                pk.r[e] = r;
            }
            #pragma unroll
            for (int mt = 0; mt < 2; ++mt) {
                h8 a = *(const h8*)(wt + (ks * 2 + mt) * 512 + lane * 8);
                acc[mt] = __builtin_amdgcn_mfma_f32_32x32x16_f16(
                    a, pk.v, acc[mt], 0, 0, 0);
            }
        }
    }

    // C/D layout (32x32): col = lane&31 (= px), row = (r&3) + 8*(r>>2) + 4*g.
    #pragma unroll
    for (int mt = 0; mt < 2; ++mt) {
        #pragma unroll
        for (int r = 0; r < 16; ++r) {
            int o = mt * 32 + (r & 3) + 8 * (r >> 2) + 4 * g;
            out[(size_t)(b * COUT + o) * HW + p] = acc[mt][r] + bias[o];
        }
    }
}

extern "C" void kernel_launch(void* const* d_in, const int* in_sizes, int n_in,
                              void* d_out, int out_size, void* d_ws, size_t ws_size,
                              hipStream_t stream) {
    const float* x      = (const float*)d_in[0];
    const float* offset = (const float*)d_in[1];
    const float* mask   = (const float*)d_in[2];
    const float* weight = (const float*)d_in[3];
    const float* bias   = (const float*)d_in[4];
    (void)d_ws; (void)ws_size;

    prep<<<Bn * Hh + 144, 256, 0, stream>>>(x, weight);
    dcn_main<<<Bn * 128, 256, 0, stream>>>(offset, mask, bias, (float*)d_out);
}